// Round 5
// baseline (1061.588 us; speedup 1.0000x reference)
//
#include <hip/hip_runtime.h>
#include <hip/hip_bf16.h>

#define H_DIM 2048
#define E_NUM 8
#define I_DIM 4096
#define TWO_I 8192
#define T_TOK 2048

typedef __bf16 bf16x8 __attribute__((ext_vector_type(8)));
typedef float f32x4 __attribute__((ext_vector_type(4)));

static __device__ __forceinline__ unsigned short f2bs(float x) {
    __hip_bfloat16 h = __float2bfloat16(x);
    return __builtin_bit_cast(unsigned short, h);
}

static __device__ __forceinline__ bf16x8 cvt8(const float* q) {
    bf16x8 r;
#pragma unroll
    for (int j = 0; j < 8; j++) r[j] = (__bf16)q[j];
    return r;
}

#define MFMA16(a, b, c) __builtin_amdgcn_mfma_f32_16x16x32_bf16(a, b, c, 0, 0, 0)

// load 8 f32 along k (stride ldb) for one B fragment
#define LDQ(dst, p, kk) { _Pragma("unroll") \
    for (int j_ = 0; j_ < 8; j_++) dst[j_] = (p)[(kk) + (size_t)j_ * ldb]; }

// ---------------- fused router + convert: one wave per token ----------------
__global__ __launch_bounds__(256) void router_convert_kernel(
    const float* __restrict__ hs, const float* __restrict__ rw,
    float* __restrict__ out_scores, int* __restrict__ eidx,
    unsigned short* __restrict__ xb, unsigned short* __restrict__ xs) {
    int tok = blockIdx.x * 4 + (threadIdx.x >> 6);
    int lane = threadIdx.x & 63;
    const float* row = hs + (size_t)tok * H_DIM;
    float4 v[8];
    float acc[E_NUM];
#pragma unroll
    for (int e = 0; e < E_NUM; e++) acc[e] = 0.f;
#pragma unroll
    for (int i = 0; i < 8; i++) {
        int hb = i * 256 + lane * 4;
        v[i] = *reinterpret_cast<const float4*>(row + hb);
        const float* w0 = rw + (size_t)hb * E_NUM;
#pragma unroll
        for (int e = 0; e < E_NUM; e++) {
            acc[e] += v[i].x * w0[e] + v[i].y * w0[E_NUM + e] +
                      v[i].z * w0[2 * E_NUM + e] + v[i].w * w0[3 * E_NUM + e];
        }
    }
#pragma unroll
    for (int e = 0; e < E_NUM; e++) {
#pragma unroll
        for (int o = 32; o > 0; o >>= 1) acc[e] += __shfl_xor(acc[e], o, 64);
    }
    int best = 0; float bv = acc[0];
#pragma unroll
    for (int e = 1; e < E_NUM; e++) { if (acc[e] > bv) { bv = acc[e]; best = e; } }
    float sc = 1.f / (1.f + expf(-bv));
    if (lane < E_NUM) out_scores[(size_t)lane * T_TOK + tok] = (lane == best) ? sc : 0.f;
    if (lane == 0) eidx[tok] = best;
    unsigned short* xbr = xb + (size_t)tok * H_DIM;
    unsigned short* xsr = xs + (size_t)tok * H_DIM;
#pragma unroll
    for (int i = 0; i < 8; i++) {
        int hb = i * 256 + lane * 4;
        ushort4 b, s4;
        b.x = f2bs(v[i].x); b.y = f2bs(v[i].y); b.z = f2bs(v[i].z); b.w = f2bs(v[i].w);
        s4.x = f2bs(v[i].x * sc); s4.y = f2bs(v[i].y * sc);
        s4.z = f2bs(v[i].z * sc); s4.w = f2bs(v[i].w * sc);
        *reinterpret_cast<ushort4*>(xbr + hb) = b;
        *reinterpret_cast<ushort4*>(xsr + hb) = s4;
    }
}

// ---------------- grouping ----------------
__global__ void group_kernel(const int* __restrict__ eidx, int* __restrict__ perm,
                             int* __restrict__ off) {
    __shared__ int cnt[E_NUM];
    __shared__ int base[E_NUM];
    int t = threadIdx.x;
    if (t < E_NUM) cnt[t] = 0;
    __syncthreads();
    for (int i = t; i < T_TOK; i += 256) atomicAdd(&cnt[eidx[i]], 1);
    __syncthreads();
    if (t == 0) {
        int s = 0;
        for (int e = 0; e < E_NUM; e++) { base[e] = s; off[e] = s; s += cnt[e]; }
        off[E_NUM] = s;
    }
    __syncthreads();
    for (int i = t; i < T_TOK; i += 256) {
        int e = eidx[i];
        int p = atomicAdd(&base[e], 1);
        perm[p] = i;
    }
}

// ---------------- GEMM1: LDS-free streaming gate_up + SwiGLU -> hmid ----------------
// 256 thr = 4 waves (2m x 2n). Wave: 64 tokens x (32 gate + 32 up cols). No LDS, no barriers.
// grid.x = I/64, grid.y = g*16 + mt (m-slot of 128 tokens)
__global__ __launch_bounds__(256, 3) void gemm1_kernel(
    const unsigned short* __restrict__ xb, const unsigned short* __restrict__ xs,
    const float* __restrict__ gup, const float* __restrict__ sg,
    const float* __restrict__ su, const int* __restrict__ perm,
    const int* __restrict__ off, unsigned short* __restrict__ hmid) {
    int nt = blockIdx.x;
    int g = blockIdx.y >> 4;
    int mt = blockIdx.y & 15;
    int rowbase, ng;
    if (g < E_NUM) { rowbase = off[g]; ng = off[g + 1] - rowbase; }
    else { rowbase = 0; ng = T_TOK; }
    int mstart = mt * 128;
    if (mstart >= ng) return;

    int tid = threadIdx.x;
    int wave = tid >> 6, lane = tid & 63;
    int wr = wave >> 1, wc = wave & 1;
    int ln = lane & 15, h = lane >> 4;

    const unsigned short* Abase = (g == E_NUM) ? xb : xs;
    int mbase = mstart + wr * 64;
    unsigned aoff0, aoff1, aoff2, aoff3;
#define MKAOFF1(i, dst) { int r_ = mbase + i * 16 + ln; r_ = (r_ < ng) ? r_ : (ng - 1); \
        int tok_ = (g < E_NUM) ? perm[rowbase + r_] : r_; dst = (unsigned)tok_ * H_DIM + h * 8; }
    MKAOFF1(0, aoff0) MKAOFF1(1, aoff1) MKAOFF1(2, aoff2) MKAOFF1(3, aoff3)

    const float* gbase; const float* ubase; size_t ldb;
    if (g < E_NUM) { gbase = gup + (size_t)g * H_DIM * TWO_I; ubase = gbase + I_DIM; ldb = TWO_I; }
    else { gbase = sg; ubase = su; ldb = I_DIM; }
    int colg = nt * 64 + wc * 32 + ln;
    const float* pg0 = gbase + (size_t)(h * 8) * ldb + colg;
    const float* pg1 = pg0 + 16;
    const float* pu0 = ubase + (size_t)(h * 8) * ldb + colg;
    const float* pu1 = pu0 + 16;

    f32x4 zero = {0.f, 0.f, 0.f, 0.f};
    f32x4 accg[4][2], accu[4][2];
#pragma unroll
    for (int i = 0; i < 4; i++)
#pragma unroll
        for (int j = 0; j < 2; j++) { accg[i][j] = zero; accu[i][j] = zero; }

    float qg0[8], qg1[8], qu0[8], qu1[8];
    bf16x8 aq0, aq1, aq2, aq3;
    const int NT = H_DIM / 32;

    // prologue: loads for t=0
    LDQ(qg0, pg0, 0); LDQ(qg1, pg1, 0); LDQ(qu0, pu0, 0); LDQ(qu1, pu1, 0);
    aq0 = *(const bf16x8*)(Abase + aoff0);
    aq1 = *(const bf16x8*)(Abase + aoff1);
    aq2 = *(const bf16x8*)(Abase + aoff2);
    aq3 = *(const bf16x8*)(Abase + aoff3);

    for (int t = 0; t < NT; ++t) {
        bf16x8 bg0 = cvt8(qg0), bg1 = cvt8(qg1), bu0 = cvt8(qu0), bu1 = cvt8(qu1);
        bf16x8 a0 = aq0, a1 = aq1, a2 = aq2, a3 = aq3;
        int tn = (t + 1 < NT) ? (t + 1) : t;
        size_t kk = (size_t)tn * 32 * ldb;
        unsigned ka = (unsigned)tn * 32;
        LDQ(qg0, pg0, kk); LDQ(qg1, pg1, kk); LDQ(qu0, pu0, kk); LDQ(qu1, pu1, kk);
        aq0 = *(const bf16x8*)(Abase + aoff0 + ka);
        aq1 = *(const bf16x8*)(Abase + aoff1 + ka);
        aq2 = *(const bf16x8*)(Abase + aoff2 + ka);
        aq3 = *(const bf16x8*)(Abase + aoff3 + ka);
#define G1_ROW(i, ai) \
        accg[i][0] = MFMA16(ai, bg0, accg[i][0]); \
        accg[i][1] = MFMA16(ai, bg1, accg[i][1]); \
        accu[i][0] = MFMA16(ai, bu0, accu[i][0]); \
        accu[i][1] = MFMA16(ai, bu1, accu[i][1]);
        G1_ROW(0, a0) G1_ROW(1, a1) G1_ROW(2, a2) G1_ROW(3, a3)
    }

    int hbase = (g < E_NUM) ? rowbase : T_TOK;
#pragma unroll
    for (int i = 0; i < 4; i++) {
#pragma unroll
        for (int jn = 0; jn < 2; jn++) {
#pragma unroll
            for (int r = 0; r < 4; r++) {
                int row = mbase + i * 16 + h * 4 + r;
                if (row < ng) {
                    float gv = accg[i][jn][r], uv = accu[i][jn][r];
                    float hv = gv / (1.f + expf(-gv)) * uv;  // silu(g)*u
                    int col = nt * 64 + wc * 32 + jn * 16 + ln;
                    hmid[(size_t)(hbase + row) * I_DIM + col] = f2bs(hv);
                }
            }
        }
    }
}

// ---------------- GEMM2: LDS-free streaming down proj ----------------
// 256 thr = 4 waves (2m x 2n). Wave: 64 rows x 64 cols. ADD=0 shared writes, ADD=1 routed +=
template <int ADD>
__global__ __launch_bounds__(256, 3) void gemm2_kernel(
    const unsigned short* __restrict__ hmid, const float* __restrict__ dwn,
    const float* __restrict__ sd, const int* __restrict__ perm,
    const int* __restrict__ off, float* __restrict__ out) {
    int nt = blockIdx.x;
    int g, mt, rowbase, ng, hbase;
    if (ADD) {
        g = blockIdx.y >> 4; mt = blockIdx.y & 15;
        rowbase = off[g]; ng = off[g + 1] - rowbase; hbase = rowbase;
    } else {
        g = E_NUM; mt = blockIdx.y; rowbase = 0; ng = T_TOK; hbase = T_TOK;
    }
    int mstart = mt * 128;
    if (mstart >= ng) return;

    int tid = threadIdx.x;
    int wave = tid >> 6, lane = tid & 63;
    int wr = wave >> 1, wc = wave & 1;
    int ln = lane & 15, h = lane >> 4;

    int mbase = mstart + wr * 64;
    unsigned aoff0, aoff1, aoff2, aoff3;
#define MKAOFF2(i, dst) { int r_ = mbase + i * 16 + ln; r_ = (r_ < ng) ? r_ : (ng - 1); \
        dst = (unsigned)(hbase + r_) * I_DIM + h * 8; }
    MKAOFF2(0, aoff0) MKAOFF2(1, aoff1) MKAOFF2(2, aoff2) MKAOFF2(3, aoff3)

    const float* bbase = ADD ? (dwn + (size_t)g * I_DIM * H_DIM) : sd;
    const size_t ldb = H_DIM;
    int coln = nt * 128 + wc * 64 + ln;
    const float* pb0 = bbase + (size_t)(h * 8) * ldb + coln;
    const float* pb1 = pb0 + 16;
    const float* pb2 = pb0 + 32;
    const float* pb3 = pb0 + 48;

    f32x4 zero = {0.f, 0.f, 0.f, 0.f};
    f32x4 acc[4][4];
#pragma unroll
    for (int i = 0; i < 4; i++)
#pragma unroll
        for (int j = 0; j < 4; j++) acc[i][j] = zero;

    float qb0[8], qb1[8], qb2[8], qb3[8];
    bf16x8 aq0, aq1, aq2, aq3;
    const int NT = I_DIM / 32;

    LDQ(qb0, pb0, 0); LDQ(qb1, pb1, 0); LDQ(qb2, pb2, 0); LDQ(qb3, pb3, 0);
    aq0 = *(const bf16x8*)(hmid + aoff0);
    aq1 = *(const bf16x8*)(hmid + aoff1);
    aq2 = *(const bf16x8*)(hmid + aoff2);
    aq3 = *(const bf16x8*)(hmid + aoff3);

    for (int t = 0; t < NT; ++t) {
        bf16x8 b0 = cvt8(qb0), b1 = cvt8(qb1), b2 = cvt8(qb2), b3 = cvt8(qb3);
        bf16x8 a0 = aq0, a1 = aq1, a2 = aq2, a3 = aq3;
        int tn = (t + 1 < NT) ? (t + 1) : t;
        size_t kk = (size_t)tn * 32 * ldb;
        unsigned ka = (unsigned)tn * 32;
        LDQ(qb0, pb0, kk); LDQ(qb1, pb1, kk); LDQ(qb2, pb2, kk); LDQ(qb3, pb3, kk);
        aq0 = *(const bf16x8*)(hmid + aoff0 + ka);
        aq1 = *(const bf16x8*)(hmid + aoff1 + ka);
        aq2 = *(const bf16x8*)(hmid + aoff2 + ka);
        aq3 = *(const bf16x8*)(hmid + aoff3 + ka);
#define G2_ROW(i, ai) \
        acc[i][0] = MFMA16(ai, b0, acc[i][0]); \
        acc[i][1] = MFMA16(ai, b1, acc[i][1]); \
        acc[i][2] = MFMA16(ai, b2, acc[i][2]); \
        acc[i][3] = MFMA16(ai, b3, acc[i][3]);
        G2_ROW(0, a0) G2_ROW(1, a1) G2_ROW(2, a2) G2_ROW(3, a3)
    }

#pragma unroll
    for (int i = 0; i < 4; i++) {
#pragma unroll
        for (int j = 0; j < 4; j++) {
#pragma unroll
            for (int r = 0; r < 4; r++) {
                int row = mbase + i * 16 + h * 4 + r;
                if (row < ng) {
                    int tok = ADD ? perm[rowbase + row] : row;
                    int col = nt * 128 + wc * 64 + j * 16 + ln;
                    float v = acc[i][j][r];
                    float* o = out + (size_t)tok * H_DIM + col;
                    if (ADD) *o += v; else *o = v;
                }
            }
        }
    }
}

extern "C" void kernel_launch(void* const* d_in, const int* in_sizes, int n_in,
                              void* d_out, int out_size, void* d_ws, size_t ws_size,
                              hipStream_t stream) {
    (void)in_sizes; (void)n_in; (void)out_size;
    const float* hs  = (const float*)d_in[0];
    const float* rw  = (const float*)d_in[1];
    const float* gup = (const float*)d_in[2];
    const float* dwn = (const float*)d_in[3];
    const float* sg  = (const float*)d_in[4];
    const float* su  = (const float*)d_in[5];
    const float* sd  = (const float*)d_in[6];
    float* out = (float*)d_out;
    float* out_scores = out + (size_t)T_TOK * H_DIM;

    char* w = (char*)d_ws;
    size_t o = 0;
    auto alloc = [&](size_t bytes) {
        void* p = w + o;
        o += (bytes + 255) & ~(size_t)255;
        return p;
    };
    unsigned short* xb   = (unsigned short*)alloc((size_t)T_TOK * H_DIM * 2);
    unsigned short* xs   = (unsigned short*)alloc((size_t)T_TOK * H_DIM * 2);
    unsigned short* hmid = (unsigned short*)alloc((size_t)2 * T_TOK * I_DIM * 2);
    int* eidx    = (int*)alloc(T_TOK * 4);
    int* perm    = (int*)alloc(T_TOK * 4);
    int* off     = (int*)alloc(64 * 4);
    if (ws_size < o) return;  // insufficient workspace

    router_convert_kernel<<<T_TOK / 4, 256, 0, stream>>>(hs, rw, out_scores, eidx, xb, xs);
    group_kernel<<<1, 256, 0, stream>>>(eidx, perm, off);

    gemm1_kernel<<<dim3(I_DIM / 64, 9 * 16), 256, 0, stream>>>(
        xb, xs, gup, sg, su, perm, off, hmid);
    gemm2_kernel<0><<<dim3(H_DIM / 128, 16), 256, 0, stream>>>(hmid, dwn, sd, perm, off, out);
    gemm2_kernel<1><<<dim3(H_DIM / 128, E_NUM * 16), 256, 0, stream>>>(hmid, dwn, sd, perm, off, out);
}

// Round 7
// 767.977 us; speedup vs baseline: 1.3823x; 1.3823x over previous
//
#include <hip/hip_runtime.h>
#include <hip/hip_bf16.h>

#define H_DIM 2048
#define E_NUM 8
#define I_DIM 4096
#define TWO_I 8192
#define T_TOK 2048

typedef __bf16 bf16x8 __attribute__((ext_vector_type(8)));
typedef float f32x4 __attribute__((ext_vector_type(4)));

static __device__ __forceinline__ unsigned short f2bs(float x) {
    __hip_bfloat16 h = __float2bfloat16(x);
    return __builtin_bit_cast(unsigned short, h);
}

#define MFMA16(a, b, c) __builtin_amdgcn_mfma_f32_16x16x32_bf16(a, b, c, 0, 0, 0)
#define BSWZ(n) (((((n) & 7) ^ (((n) >> 2) & 7))) << 4)
// barrier WITHOUT vmcnt drain: LDS ops visible, global loads stay in flight
#define BARRIER() asm volatile("s_waitcnt lgkmcnt(0)\ns_barrier" ::: "memory")

static __device__ __forceinline__ bf16x8 bload(
    const unsigned short* __restrict__ Bs, int n, int s, int h) {
    int off = (n * 128 + s * 64 + h * 16) ^ BSWZ(n);
    return *reinterpret_cast<const bf16x8*>((const char*)Bs + off);
}

// ---------------- fused router + convert: one wave per token ----------------
__global__ __launch_bounds__(256) void router_convert_kernel(
    const float* __restrict__ hs, const float* __restrict__ rw,
    float* __restrict__ out_scores, int* __restrict__ eidx,
    unsigned short* __restrict__ xb, unsigned short* __restrict__ xs) {
    int tok = blockIdx.x * 4 + (threadIdx.x >> 6);
    int lane = threadIdx.x & 63;
    const float* row = hs + (size_t)tok * H_DIM;
    float4 v[8];
    float acc[E_NUM];
#pragma unroll
    for (int e = 0; e < E_NUM; e++) acc[e] = 0.f;
#pragma unroll
    for (int i = 0; i < 8; i++) {
        int hb = i * 256 + lane * 4;
        v[i] = *reinterpret_cast<const float4*>(row + hb);
        const float* w0 = rw + (size_t)hb * E_NUM;
#pragma unroll
        for (int e = 0; e < E_NUM; e++) {
            acc[e] += v[i].x * w0[e] + v[i].y * w0[E_NUM + e] +
                      v[i].z * w0[2 * E_NUM + e] + v[i].w * w0[3 * E_NUM + e];
        }
    }
#pragma unroll
    for (int e = 0; e < E_NUM; e++) {
#pragma unroll
        for (int o = 32; o > 0; o >>= 1) acc[e] += __shfl_xor(acc[e], o, 64);
    }
    int best = 0; float bv = acc[0];
#pragma unroll
    for (int e = 1; e < E_NUM; e++) { if (acc[e] > bv) { bv = acc[e]; best = e; } }
    float sc = 1.f / (1.f + expf(-bv));
    if (lane < E_NUM) out_scores[(size_t)lane * T_TOK + tok] = (lane == best) ? sc : 0.f;
    if (lane == 0) eidx[tok] = best;
    unsigned short* xbr = xb + (size_t)tok * H_DIM;
    unsigned short* xsr = xs + (size_t)tok * H_DIM;
#pragma unroll
    for (int i = 0; i < 8; i++) {
        int hb = i * 256 + lane * 4;
        ushort4 b, s4;
        b.x = f2bs(v[i].x); b.y = f2bs(v[i].y); b.z = f2bs(v[i].z); b.w = f2bs(v[i].w);
        s4.x = f2bs(v[i].x * sc); s4.y = f2bs(v[i].y * sc);
        s4.z = f2bs(v[i].z * sc); s4.w = f2bs(v[i].w * sc);
        *reinterpret_cast<ushort4*>(xbr + hb) = b;
        *reinterpret_cast<ushort4*>(xsr + hb) = s4;
    }
}

// ---------------- grouping ----------------
__global__ void group_kernel(const int* __restrict__ eidx, int* __restrict__ perm,
                             int* __restrict__ off) {
    __shared__ int cnt[E_NUM];
    __shared__ int base[E_NUM];
    int t = threadIdx.x;
    if (t < E_NUM) cnt[t] = 0;
    __syncthreads();
    for (int i = t; i < T_TOK; i += 256) atomicAdd(&cnt[eidx[i]], 1);
    __syncthreads();
    if (t == 0) {
        int s = 0;
        for (int e = 0; e < E_NUM; e++) { base[e] = s; off[e] = s; s += cnt[e]; }
        off[E_NUM] = s;
    }
    __syncthreads();
    for (int i = t; i < T_TOK; i += 256) {
        int e = eidx[i];
        int p = atomicAdd(&base[e], 1);
        perm[p] = i;
    }
}

// ---------------- GEMM1: stream gate_up f32 -> LDS bf16, A direct; SwiGLU -> hmid
// 256 thr = 4 m-waves x 64 rows (BM=256). BN=32 (32 gate + 32 up cols). BK=64.
// grid.x = I/32 (128), grid.y = g*8 + mt
__global__ __launch_bounds__(256, 3) void gemm1_kernel(
    const unsigned short* __restrict__ xb, const unsigned short* __restrict__ xs,
    const float* __restrict__ gup, const float* __restrict__ sg,
    const float* __restrict__ su, const int* __restrict__ perm,
    const int* __restrict__ off, unsigned short* __restrict__ hmid) {
    int nt = blockIdx.x;
    int g = blockIdx.y >> 3;
    int mt = blockIdx.y & 7;
    int rowbase, ng;
    if (g < E_NUM) { rowbase = off[g]; ng = off[g + 1] - rowbase; }
    else { rowbase = 0; ng = T_TOK; }
    int mstart = mt * 256;
    if (mstart >= ng) return;

    __shared__ unsigned short Bg[32 * 64];   // 4 KB
    __shared__ unsigned short Bu[32 * 64];   // 4 KB

    int tid = threadIdx.x;
    int wave = tid >> 6, lane = tid & 63;
    int ln = lane & 15, h = lane >> 4;

    // A row pointers (4 row-frags per wave), k-contiguous bf16
    const unsigned short* Abase = (g == E_NUM) ? xb : xs;
    const unsigned short* Ap0; const unsigned short* Ap1;
    const unsigned short* Ap2; const unsigned short* Ap3;
#define MKAP(i, dst) { int r_ = mstart + wave * 64 + i * 16 + ln; \
        r_ = (r_ < ng) ? r_ : (ng - 1); \
        int tok_ = (g < E_NUM) ? perm[rowbase + r_] : r_; \
        dst = Abase + (size_t)tok_ * H_DIM + h * 8; }
    MKAP(0, Ap0) MKAP(1, Ap1) MKAP(2, Ap2) MKAP(3, Ap3)
#undef MKAP

    const float* gbase; const float* ubase; size_t ldb;
    if (g < E_NUM) {
        gbase = gup + (size_t)g * H_DIM * TWO_I + nt * 32;
        ubase = gbase + I_DIM;
        ldb = TWO_I;
    } else {
        gbase = sg + nt * 32;
        ubase = su + nt * 32;
        ldb = I_DIM;
    }
    // B stage mapping: thread -> 2 k-rows x 4 n-cols per tile
    int nb = (tid & 7) * 4;
    int kk = (tid >> 3) * 2;
    const float* pg = gbase + (size_t)kk * ldb + nb;
    const float* pu = ubase + (size_t)kk * ldb + nb;

    f32x4 zero = {0.f, 0.f, 0.f, 0.f};
    f32x4 accg[4][2], accu[4][2];
#pragma unroll
    for (int i = 0; i < 4; i++)
#pragma unroll
        for (int j = 0; j < 2; j++) { accg[i][j] = zero; accu[i][j] = zero; }

    const int NT = H_DIM / 64;
    f32x4 qg0, qg1, qu0, qu1;
    bf16x8 aA0, aA1, aA2, aA3, aB0, aB1, aB2, aB3;

    // prologue: B f32 regs for tile 0, A frags for (t0,s0)
    qg0 = *reinterpret_cast<const f32x4*>(pg);
    qg1 = *reinterpret_cast<const f32x4*>(pg + ldb);
    qu0 = *reinterpret_cast<const f32x4*>(pu);
    qu1 = *reinterpret_cast<const f32x4*>(pu + ldb);
    aA0 = *(const bf16x8*)(Ap0); aA1 = *(const bf16x8*)(Ap1);
    aA2 = *(const bf16x8*)(Ap2); aA3 = *(const bf16x8*)(Ap3);

    for (int t = 0; t < NT; ++t) {
        // write B(t) regs -> LDS (transposed, swizzled)
#pragma unroll
        for (int i = 0; i < 4; i++) {
            int n = nb + i;
            unsigned og = (unsigned)f2bs(qg0[i]) | ((unsigned)f2bs(qg1[i]) << 16);
            unsigned ou = (unsigned)f2bs(qu0[i]) | ((unsigned)f2bs(qu1[i]) << 16);
            int ob = (n * 128 + kk * 2) ^ BSWZ(n);
            *reinterpret_cast<unsigned*>((char*)Bg + ob) = og;
            *reinterpret_cast<unsigned*>((char*)Bu + ob) = ou;
        }
        // prefetch A(t, s=1) — crosses barrier, consumed after s=0 compute
        unsigned kof = (unsigned)t * 64;
        aB0 = *(const bf16x8*)(Ap0 + kof + 32); aB1 = *(const bf16x8*)(Ap1 + kof + 32);
        aB2 = *(const bf16x8*)(Ap2 + kof + 32); aB3 = *(const bf16x8*)(Ap3 + kof + 32);
        BARRIER();   // B(t) visible; global loads stay in flight
        // issue B f32 loads for tile t+1 (consumed at next iter's write phase)
        int tn = (t + 1 < NT) ? t + 1 : t;
        {
            size_t ko = (size_t)tn * 64 * ldb;
            qg0 = *reinterpret_cast<const f32x4*>(pg + ko);
            qg1 = *reinterpret_cast<const f32x4*>(pg + ko + ldb);
            qu0 = *reinterpret_cast<const f32x4*>(pu + ko);
            qu1 = *reinterpret_cast<const f32x4*>(pu + ko + ldb);
        }
        // s = 0 : compute with aA
        {
            bf16x8 bg0 = bload(Bg, ln, 0, h), bg1 = bload(Bg, 16 + ln, 0, h);
            bf16x8 bu0 = bload(Bu, ln, 0, h), bu1 = bload(Bu, 16 + ln, 0, h);
            accg[0][0] = MFMA16(aA0, bg0, accg[0][0]); accg[0][1] = MFMA16(aA0, bg1, accg[0][1]);
            accu[0][0] = MFMA16(aA0, bu0, accu[0][0]); accu[0][1] = MFMA16(aA0, bu1, accu[0][1]);
            accg[1][0] = MFMA16(aA1, bg0, accg[1][0]); accg[1][1] = MFMA16(aA1, bg1, accg[1][1]);
            accu[1][0] = MFMA16(aA1, bu0, accu[1][0]); accu[1][1] = MFMA16(aA1, bu1, accu[1][1]);
            accg[2][0] = MFMA16(aA2, bg0, accg[2][0]); accg[2][1] = MFMA16(aA2, bg1, accg[2][1]);
            accu[2][0] = MFMA16(aA2, bu0, accu[2][0]); accu[2][1] = MFMA16(aA2, bu1, accu[2][1]);
            accg[3][0] = MFMA16(aA3, bg0, accg[3][0]); accg[3][1] = MFMA16(aA3, bg1, accg[3][1]);
            accu[3][0] = MFMA16(aA3, bu0, accu[3][0]); accu[3][1] = MFMA16(aA3, bu1, accu[3][1]);
        }
        // prefetch A(t+1, s=0) into aA (consumed next iter)
        {
            unsigned kof2 = (unsigned)tn * 64;
            aA0 = *(const bf16x8*)(Ap0 + kof2); aA1 = *(const bf16x8*)(Ap1 + kof2);
            aA2 = *(const bf16x8*)(Ap2 + kof2); aA3 = *(const bf16x8*)(Ap3 + kof2);
        }
        // s = 1 : compute with aB
        {
            bf16x8 bg0 = bload(Bg, ln, 1, h), bg1 = bload(Bg, 16 + ln, 1, h);
            bf16x8 bu0 = bload(Bu, ln, 1, h), bu1 = bload(Bu, 16 + ln, 1, h);
            accg[0][0] = MFMA16(aB0, bg0, accg[0][0]); accg[0][1] = MFMA16(aB0, bg1, accg[0][1]);
            accu[0][0] = MFMA16(aB0, bu0, accu[0][0]); accu[0][1] = MFMA16(aB0, bu1, accu[0][1]);
            accg[1][0] = MFMA16(aB1, bg0, accg[1][0]); accg[1][1] = MFMA16(aB1, bg1, accg[1][1]);
            accu[1][0] = MFMA16(aB1, bu0, accu[1][0]); accu[1][1] = MFMA16(aB1, bu1, accu[1][1]);
            accg[2][0] = MFMA16(aB2, bg0, accg[2][0]); accg[2][1] = MFMA16(aB2, bg1, accg[2][1]);
            accu[2][0] = MFMA16(aB2, bu0, accu[2][0]); accu[2][1] = MFMA16(aB2, bu1, accu[2][1]);
            accg[3][0] = MFMA16(aB3, bg0, accg[3][0]); accg[3][1] = MFMA16(aB3, bg1, accg[3][1]);
            accu[3][0] = MFMA16(aB3, bu0, accu[3][0]); accu[3][1] = MFMA16(aB3, bu1, accu[3][1]);
        }
        BARRIER();   // my B reads done (lgkm==0 already); no vmcnt drain
    }

    int hbase = (g < E_NUM) ? rowbase : T_TOK;
#pragma unroll
    for (int i = 0; i < 4; i++) {
#pragma unroll
        for (int jn = 0; jn < 2; jn++) {
#pragma unroll
            for (int r = 0; r < 4; r++) {
                int row = mstart + wave * 64 + i * 16 + h * 4 + r;
                if (row < ng) {
                    float gv = accg[i][jn][r], uv = accu[i][jn][r];
                    float hv = gv / (1.f + expf(-gv)) * uv;  // silu(g)*u
                    int col = nt * 32 + jn * 16 + ln;
                    hmid[(size_t)(hbase + row) * I_DIM + col] = f2bs(hv);
                }
            }
        }
    }
}

// ---------------- GEMM2: down proj, same streaming structure ----------------
// 256 thr = 4 m-waves x 64 rows (BM=256). BN=64. BK=64.
// ADD=0: shared writes (grid.y = mt 0..7); ADD=1: routed accum (grid.y = g*8+mt)
template <int ADD>
__global__ __launch_bounds__(256, 3) void gemm2_kernel(
    const unsigned short* __restrict__ hmid, const float* __restrict__ dwn,
    const float* __restrict__ sd, const int* __restrict__ perm,
    const int* __restrict__ off, float* __restrict__ out) {
    int nt = blockIdx.x;
    int g, mt, rowbase, ng, hbase;
    if (ADD) {
        g = blockIdx.y >> 3; mt = blockIdx.y & 7;
        rowbase = off[g]; ng = off[g + 1] - rowbase; hbase = rowbase;
    } else {
        g = E_NUM; mt = blockIdx.y; rowbase = 0; ng = T_TOK; hbase = T_TOK;
    }
    int mstart = mt * 256;
    if (mstart >= ng) return;

    __shared__ unsigned short Bs[64 * 64];   // 8 KB

    int tid = threadIdx.x;
    int wave = tid >> 6, lane = tid & 63;
    int ln = lane & 15, h = lane >> 4;

    const unsigned short* Ap0; const unsigned short* Ap1;
    const unsigned short* Ap2; const unsigned short* Ap3;
#define MKAP2(i, dst) { int r_ = mstart + wave * 64 + i * 16 + ln; \
        r_ = (r_ < ng) ? r_ : (ng - 1); \
        dst = hmid + (size_t)(hbase + r_) * I_DIM + h * 8; }
    MKAP2(0, Ap0) MKAP2(1, Ap1) MKAP2(2, Ap2) MKAP2(3, Ap3)
#undef MKAP2

    const float* bbase = (ADD ? (dwn + (size_t)g * I_DIM * H_DIM) : sd) + nt * 64;
    const size_t ldb = H_DIM;
    int nb = (tid & 15) * 4;
    int kk = (tid >> 4) * 4;
    const float* pb = bbase + (size_t)kk * ldb + nb;

    f32x4 zero = {0.f, 0.f, 0.f, 0.f};
    f32x4 acc[4][4];
#pragma unroll
    for (int i = 0; i < 4; i++)
#pragma unroll
        for (int j = 0; j < 4; j++) acc[i][j] = zero;

    const int NT = I_DIM / 64;
    f32x4 qb0, qb1, qb2, qb3;
    bf16x8 aA0, aA1, aA2, aA3, aB0, aB1, aB2, aB3;

    qb0 = *reinterpret_cast<const f32x4*>(pb);
    qb1 = *reinterpret_cast<const f32x4*>(pb + ldb);
    qb2 = *reinterpret_cast<const f32x4*>(pb + 2 * ldb);
    qb3 = *reinterpret_cast<const f32x4*>(pb + 3 * ldb);
    aA0 = *(const bf16x8*)(Ap0); aA1 = *(const bf16x8*)(Ap1);
    aA2 = *(const bf16x8*)(Ap2); aA3 = *(const bf16x8*)(Ap3);

    for (int t = 0; t < NT; ++t) {
#pragma unroll
        for (int i = 0; i < 4; i++) {
            int n = nb + i;
            ushort4 o;
            o.x = f2bs(qb0[i]); o.y = f2bs(qb1[i]);
            o.z = f2bs(qb2[i]); o.w = f2bs(qb3[i]);
            int ob = (n * 128 + kk * 2) ^ BSWZ(n);
            *reinterpret_cast<ushort4*>((char*)Bs + ob) = o;
        }
        unsigned kof = (unsigned)t * 64;
        aB0 = *(const bf16x8*)(Ap0 + kof + 32); aB1 = *(const bf16x8*)(Ap1 + kof + 32);
        aB2 = *(const bf16x8*)(Ap2 + kof + 32); aB3 = *(const bf16x8*)(Ap3 + kof + 32);
        BARRIER();
        int tn = (t + 1 < NT) ? t + 1 : t;
        {
            size_t ko = (size_t)tn * 64 * ldb;
            qb0 = *reinterpret_cast<const f32x4*>(pb + ko);
            qb1 = *reinterpret_cast<const f32x4*>(pb + ko + ldb);
            qb2 = *reinterpret_cast<const f32x4*>(pb + ko + 2 * ldb);
            qb3 = *reinterpret_cast<const f32x4*>(pb + ko + 3 * ldb);
        }
        // s = 0
        {
            bf16x8 b0 = bload(Bs, ln, 0, h), b1 = bload(Bs, 16 + ln, 0, h);
            bf16x8 b2 = bload(Bs, 32 + ln, 0, h), b3 = bload(Bs, 48 + ln, 0, h);
            acc[0][0] = MFMA16(aA0, b0, acc[0][0]); acc[0][1] = MFMA16(aA0, b1, acc[0][1]);
            acc[0][2] = MFMA16(aA0, b2, acc[0][2]); acc[0][3] = MFMA16(aA0, b3, acc[0][3]);
            acc[1][0] = MFMA16(aA1, b0, acc[1][0]); acc[1][1] = MFMA16(aA1, b1, acc[1][1]);
            acc[1][2] = MFMA16(aA1, b2, acc[1][2]); acc[1][3] = MFMA16(aA1, b3, acc[1][3]);
            acc[2][0] = MFMA16(aA2, b0, acc[2][0]); acc[2][1] = MFMA16(aA2, b1, acc[2][1]);
            acc[2][2] = MFMA16(aA2, b2, acc[2][2]); acc[2][3] = MFMA16(aA2, b3, acc[2][3]);
            acc[3][0] = MFMA16(aA3, b0, acc[3][0]); acc[3][1] = MFMA16(aA3, b1, acc[3][1]);
            acc[3][2] = MFMA16(aA3, b2, acc[3][2]); acc[3][3] = MFMA16(aA3, b3, acc[3][3]);
        }
        {
            unsigned kof2 = (unsigned)tn * 64;
            aA0 = *(const bf16x8*)(Ap0 + kof2); aA1 = *(const bf16x8*)(Ap1 + kof2);
            aA2 = *(const bf16x8*)(Ap2 + kof2); aA3 = *(const bf16x8*)(Ap3 + kof2);
        }
        // s = 1
        {
            bf16x8 b0 = bload(Bs, ln, 1, h), b1 = bload(Bs, 16 + ln, 1, h);
            bf16x8 b2 = bload(Bs, 32 + ln, 1, h), b3 = bload(Bs, 48 + ln, 1, h);
            acc[0][0] = MFMA16(aB0, b0, acc[0][0]); acc[0][1] = MFMA16(aB0, b1, acc[0][1]);
            acc[0][2] = MFMA16(aB0, b2, acc[0][2]); acc[0][3] = MFMA16(aB0, b3, acc[0][3]);
            acc[1][0] = MFMA16(aB1, b0, acc[1][0]); acc[1][1] = MFMA16(aB1, b1, acc[1][1]);
            acc[1][2] = MFMA16(aB1, b2, acc[1][2]); acc[1][3] = MFMA16(aB1, b3, acc[1][3]);
            acc[2][0] = MFMA16(aB2, b0, acc[2][0]); acc[2][1] = MFMA16(aB2, b1, acc[2][1]);
            acc[2][2] = MFMA16(aB2, b2, acc[2][2]); acc[2][3] = MFMA16(aB2, b3, acc[2][3]);
            acc[3][0] = MFMA16(aB3, b0, acc[3][0]); acc[3][1] = MFMA16(aB3, b1, acc[3][1]);
            acc[3][2] = MFMA16(aB3, b2, acc[3][2]); acc[3][3] = MFMA16(aB3, b3, acc[3][3]);
        }
        BARRIER();
    }

#pragma unroll
    for (int i = 0; i < 4; i++) {
#pragma unroll
        for (int j = 0; j < 4; j++) {
#pragma unroll
            for (int r = 0; r < 4; r++) {
                int row = mstart + wave * 64 + i * 16 + h * 4 + r;
                if (row < ng) {
                    int tok = ADD ? perm[rowbase + row] : row;
                    int col = nt * 64 + j * 16 + ln;
                    float v = acc[i][j][r];
                    float* o = out + (size_t)tok * H_DIM + col;
                    if (ADD) *o += v; else *o = v;
                }
            }
        }
    }
}

extern "C" void kernel_launch(void* const* d_in, const int* in_sizes, int n_in,
                              void* d_out, int out_size, void* d_ws, size_t ws_size,
                              hipStream_t stream) {
    (void)in_sizes; (void)n_in; (void)out_size;
    const float* hs  = (const float*)d_in[0];
    const float* rw  = (const float*)d_in[1];
    const float* gup = (const float*)d_in[2];
    const float* dwn = (const float*)d_in[3];
    const float* sg  = (const float*)d_in[4];
    const float* su  = (const float*)d_in[5];
    const float* sd  = (const float*)d_in[6];
    float* out = (float*)d_out;
    float* out_scores = out + (size_t)T_TOK * H_DIM;

    char* w = (char*)d_ws;
    size_t o = 0;
    auto alloc = [&](size_t bytes) {
        void* p = w + o;
        o += (bytes + 255) & ~(size_t)255;
        return p;
    };
    unsigned short* xb   = (unsigned short*)alloc((size_t)T_TOK * H_DIM * 2);
    unsigned short* xs   = (unsigned short*)alloc((size_t)T_TOK * H_DIM * 2);
    unsigned short* hmid = (unsigned short*)alloc((size_t)2 * T_TOK * I_DIM * 2);
    int* eidx    = (int*)alloc(T_TOK * 4);
    int* perm    = (int*)alloc(T_TOK * 4);
    int* off     = (int*)alloc(64 * 4);
    if (ws_size < o) return;  // insufficient workspace

    router_convert_kernel<<<T_TOK / 4, 256, 0, stream>>>(hs, rw, out_scores, eidx, xb, xs);
    group_kernel<<<1, 256, 0, stream>>>(eidx, perm, off);

    gemm1_kernel<<<dim3(I_DIM / 32, 9 * 8), 256, 0, stream>>>(
        xb, xs, gup, sg, su, perm, off, hmid);
    gemm2_kernel<0><<<dim3(H_DIM / 64, 8), 256, 0, stream>>>(hmid, dwn, sd, perm, off, out);
    gemm2_kernel<1><<<dim3(H_DIM / 64, E_NUM * 8), 256, 0, stream>>>(hmid, dwn, sd, perm, off, out);
}